// Round 3
// baseline (1365.049 us; speedup 1.0000x reference)
//
#include <hip/hip_runtime.h>

#define Bn  32
#define Nn  12000
#define Tn  20000
#define N1n 4000
#define N2n 1000
#define NXn 5000   // N1+N2

// ---------------- workspace layout (floats) ----------------
#define OFF_PT    0
#define OFF_DYZT  1152000
#define OFF_CY    1792000
#define OFF_CZ    1920000
#define OFF_VOL   2080000
#define OFF_VOLC  2080032
#define OFF_A     2080064
#define OFF_FY    2080096
#define OFF_FZ    2080128

// ---------------- K0: build PT[i][c][b] + vol_const (fused) ----------------
#define NPREP 4500   // 4500*256 == Nn*96 exactly
__global__ void k_init(const float* __restrict__ x, const float* __restrict__ y,
                       const float* __restrict__ pz, const int* __restrict__ tri,
                       float* __restrict__ PT, float* __restrict__ volc)
{
  if (blockIdx.x < NPREP) {
    int idx = blockIdx.x * 256 + threadIdx.x;
    int b  = idx & 31;
    int rc = idx >> 5;           // i*3 + c
    int i  = rc / 3;
    int c  = rc - i * 3;
    float v;
    if (i < N1n) {
      v = x[(size_t)b * (N1n * 3) + i * 3 + c];
    } else if (i < NXn) {
      v = (c == 1) ? pz[3 * i + 1]
                   : y[(size_t)b * (N2n * 2) + (i - N1n) * 2 + (c >> 1)];
    } else {
      v = pz[3 * i + c];
    }
    PT[idx] = v;
    return;
  }
  // vol_const part
  int t = (blockIdx.x - NPREP) * 256 + threadIdx.x;
  float acc = 0.f;
  if (t < Tn) {
    int i0 = tri[3 * t], i1 = tri[3 * t + 1], i2 = tri[3 * t + 2];
    float q0x = pz[3 * i0], q0y = pz[3 * i0 + 1], q0z = pz[3 * i0 + 2];
    float q1x = pz[3 * i1], q1y = pz[3 * i1 + 1], q1z = pz[3 * i1 + 2];
    float q2x = pz[3 * i2], q2y = pz[3 * i2 + 1], q2z = pz[3 * i2 + 2];
    float dy0 = ((q0x - q1x) * (q2z - q1z) - (q0z - q1z) * (q2x - q1x)) * (1.0f / 6.0f);
    acc = (q0y + q1y + q2y) * dy0;
  }
  __shared__ float red[256];
  red[threadIdx.x] = acc;
  __syncthreads();
  for (int off = 128; off; off >>= 1) {
    if (threadIdx.x < off) red[threadIdx.x] += red[threadIdx.x + off];
    __syncthreads();
  }
  if (threadIdx.x == 0) atomicAdd(volc, red[0]);
}

// ---------------- K1: dy (t-major [t][b]) + per-batch volume ----------------
__global__ void k_dy_vol(const float* __restrict__ PT, const int* __restrict__ tri,
                         float* __restrict__ dyT, float* __restrict__ vol)
{
  const int tid = threadIdx.x;
  const int b  = tid & 31;
  const int tl = tid >> 5;           // 0..7
  float accV = 0.f;
  for (int t = blockIdx.x * 8 + tl; t < Tn; t += gridDim.x * 8) {
    const int i0 = tri[3 * t], i1 = tri[3 * t + 1], i2 = tri[3 * t + 2];
    const float* P0 = PT + (size_t)i0 * 96;
    const float* P1 = PT + (size_t)i1 * 96;
    const float* P2 = PT + (size_t)i2 * 96;
    float p0x = P0[b], p0y = P0[32 + b], p0z = P0[64 + b];
    float p1x = P1[b], p1y = P1[32 + b], p1z = P1[64 + b];
    float p2x = P2[b], p2y = P2[32 + b], p2z = P2[64 + b];
    float dy = ((p0x - p1x) * (p2z - p1z) - (p0z - p1z) * (p2x - p1x)) * (1.0f / 6.0f);
    dyT[(size_t)t * 32 + b] = dy;
    accV += (p0y + p1y + p2y) * dy;
  }
  __shared__ float red[256];
  red[tid] = accV;
  __syncthreads();
  if (tl == 0) {
    float s = accV;
    #pragma unroll
    for (int q = 1; q < 8; ++q) s += red[q * 32 + b];
    atomicAdd(&vol[b], s);
  }
}

// ---------------- K3: dz (t-major) with corrected y ----------------
__global__ void k_dz(const float* __restrict__ PT, const int* __restrict__ tri,
                     const float* __restrict__ cy, const float* __restrict__ fy,
                     float* __restrict__ dzT)
{
  const int tid = threadIdx.x;
  const int b  = tid & 31;
  const int tl = tid >> 5;
  const float fyb = fy[b];
  for (int t = blockIdx.x * 8 + tl; t < Tn; t += gridDim.x * 8) {
    const int i0 = tri[3 * t], i1 = tri[3 * t + 1], i2 = tri[3 * t + 2];
    const float* P0 = PT + (size_t)i0 * 96;
    const float* P1 = PT + (size_t)i1 * 96;
    const float* P2 = PT + (size_t)i2 * 96;
    float p0x = P0[b], p0y = P0[32 + b];
    float p1x = P1[b], p1y = P1[32 + b];
    float p2x = P2[b], p2y = P2[32 + b];
    if (i0 < N1n) p0y += cy[(size_t)i0 * 32 + b] * fyb;
    if (i1 < N1n) p1y += cy[(size_t)i1 * 32 + b] * fyb;
    if (i2 < N1n) p2y += cy[(size_t)i2 * 32 + b] * fyb;
    float dz = ((p0x - p2x) * (p1y - p2y) - (p0y - p2y) * (p1x - p2x)) * (1.0f / 6.0f);
    dzT[(size_t)t * 32 + b] = dz;
  }
}

// ---------------- split-K GEMM: C[j][b] += sum_t A[t][b] * V[j][t] ----------------
// 4 wave-AUTONOMOUS waves per block (no barriers in main loop).
// Each wave: full 32b x 128j tile for its k-slice; lane = (bg 0..3) x (jg 0..15);
// thread tile 8b x 8j -> 64 B LDS per 64 FMA (1 B/FMA).
// Private per-wave LDS: sB[16][132] + sA[16][32]. End: LDS merge, wave0 atomics.
#define GKT 16      // k per LDS tile
#define GJT 128     // j per block
#define GKS 25      // k-splits
#define GKC 800     // Tn/GKS
#define SBP 132     // sB row stride (floats); rows 16B-aligned, writes 2-way max
#define WFL 2624    // per-wave floats: 16*132 + 16*32

__global__ __launch_bounds__(256, 3)
void k_gemm(const float* __restrict__ A,   // [Tn][32] t-major
            const float* __restrict__ V,   // [NJ][Tn]
            float* __restrict__ C,         // [NJ][32] j-major
            int NJ)
{
  __shared__ float smem[4 * WFL];          // 41984 B -> 3 blocks/CU
  const int tid  = threadIdx.x;
  const int w    = tid >> 6;
  const int lane = tid & 63;
  const int jg   = lane & 15;
  const int bg   = lane >> 4;
  const int jb   = blockIdx.y * GJT;
  const int t0   = blockIdx.x * GKC;
  float* sB = smem + w * WFL;
  float* sA = sB + GKT * SBP;

  const int cq = lane & 3;                 // V-staging: 16B chunk id
  const int r0 = lane >> 2;                // V-staging: row 0..15

  float acc[64];
  #pragma unroll
  for (int q = 0; q < 64; ++q) acc[q] = 0.f;

  for (int n = w; n < GKC / GKT; n += 4) { // 50 tiles, wave w takes n%4==w
    const int tk = t0 + n * GKT;
    // ---- stage V tile: rows jb..jb+127, cols tk..tk+15 (transpose to sB[k][j])
    #pragma unroll
    for (int p = 0; p < 8; ++p) {
      const int r = r0 + p * 16;
      float4 v = make_float4(0.f, 0.f, 0.f, 0.f);
      if (jb + r < NJ) v = *(const float4*)(V + (size_t)(jb + r) * Tn + tk + cq * 4);
      sB[(cq * 4 + 0) * SBP + r] = v.x;
      sB[(cq * 4 + 1) * SBP + r] = v.y;
      sB[(cq * 4 + 2) * SBP + r] = v.z;
      sB[(cq * 4 + 3) * SBP + r] = v.w;
    }
    // ---- stage A tile: 16k x 32b contiguous
    {
      const float* ap = A + (size_t)tk * 32 + lane * 8;
      float4 a0 = *(const float4*)(ap);
      float4 a1 = *(const float4*)(ap + 4);
      *(float4*)(sA + lane * 8)     = a0;
      *(float4*)(sA + lane * 8 + 4) = a1;
    }
    // ---- compute (in-wave LDS ordering; no barrier)
    #pragma unroll
    for (int kk = 0; kk < GKT; ++kk) {
      float4 a0 = *(const float4*)(sA + kk * 32 + bg * 8);
      float4 a1 = *(const float4*)(sA + kk * 32 + bg * 8 + 4);
      float4 b0 = *(const float4*)(sB + kk * SBP + jg * 4);
      float4 b1 = *(const float4*)(sB + kk * SBP + 64 + jg * 4);
      const float av[8] = {a0.x, a0.y, a0.z, a0.w, a1.x, a1.y, a1.z, a1.w};
      const float bv[8] = {b0.x, b0.y, b0.z, b0.w, b1.x, b1.y, b1.z, b1.w};
      #pragma unroll
      for (int i = 0; i < 8; ++i) {
        #pragma unroll
        for (int j = 0; j < 8; ++j)
          acc[i * 8 + j] += av[i] * bv[j];
      }
    }
  }

  // ---- merge 4 waves' partials (2 halves), wave0 does the atomics
  #pragma unroll
  for (int half = 0; half < 2; ++half) {
    __syncthreads();
    if (w > 0) {
      #pragma unroll
      for (int q = 0; q < 32; ++q)
        smem[(w - 1) * 2112 + lane * 33 + q] = acc[half * 32 + q];
    }
    __syncthreads();
    if (w == 0) {
      #pragma unroll
      for (int q = 0; q < 32; ++q) {
        const int li = half * 32 + q;
        float s = acc[li]
                + smem[0 * 2112 + lane * 33 + q]
                + smem[1 * 2112 + lane * 33 + q]
                + smem[2 * 2112 + lane * 33 + q];
        const int i  = li >> 3;          // b sub-index
        const int jj = li & 7;           // j sub-index
        const int jgl = jb + (jj >> 2) * 64 + jg * 4 + (jj & 3);
        if (jgl < NJ) atomicAdd(&C[(size_t)jgl * 32 + bg * 8 + i], s);
      }
    }
  }
}

// ---------------- K2/K4: s[b] = sum_j coeff[j][b]^2 ; factor = a / s ----------------
__global__ void k_factor(const float* __restrict__ coeff, int NJ,
    const float* __restrict__ vol, const float* __restrict__ volc,
    float* __restrict__ aArr, float* __restrict__ factor, int computeA)
{
  const int tid = threadIdx.x;
  const int b = tid & 31, g = tid >> 5;    // 32 j-groups
  float s = 0.f;
  for (int j = g; j < NJ; j += 32) {
    float v = coeff[(size_t)j * 32 + b];
    s += v * v;
  }
  __shared__ float red[1024];
  red[tid] = s;
  __syncthreads();
  if (tid < 32) {
    float t = red[tid];
    #pragma unroll
    for (int q = 1; q < 32; ++q) t += red[q * 32 + tid];
    float a;
    if (computeA) { a = 0.5f * (volc[0] - vol[tid]); aArr[tid] = a; }
    else          { a = aArr[tid]; }
    factor[tid] = a / t;
  }
}

// ---------------- K5: assemble outputs ----------------
__global__ void k_out(const float* __restrict__ x, const float* __restrict__ y,
    const float* __restrict__ cy, const float* __restrict__ cz,
    const float* __restrict__ fy, const float* __restrict__ fz,
    float* __restrict__ out)
{
  int idx = blockIdx.x * blockDim.x + threadIdx.x;
  if (idx >= 448000) return;
  if (idx < 384000) {
    int b = idx / 12000;
    int r = idx - b * 12000;
    int i = r / 3, c = r - i * 3;
    float v = x[(size_t)b * 12000 + r];
    if (c == 1)      v += cy[(size_t)i * 32 + b] * fy[b];
    else if (c == 2) v += cz[(size_t)i * 32 + b] * fz[b];
    out[idx] = v;
  } else {
    int k = idx - 384000;
    int b = k / 2000;
    int r = k - b * 2000;
    int i = r >> 1, c = r & 1;
    float v = y[(size_t)b * 2000 + r];
    if (c) v += cz[(size_t)(N1n + i) * 32 + b] * fz[b];
    out[idx] = v;
  }
}

// ---------------- launch ----------------
extern "C" void kernel_launch(void* const* d_in, const int* in_sizes, int n_in,
                              void* d_out, int out_size, void* d_ws, size_t ws_size,
                              hipStream_t stream)
{
  const float* x   = (const float*)d_in[0];
  const float* y   = (const float*)d_in[1];
  const float* pz  = (const float*)d_in[2];
  const int*   tri = (const int*)d_in[3];
  const float* Vx  = (const float*)d_in[6];   // [N1][T]
  const float* Vxy = (const float*)d_in[7];   // [N1+N2][T]
  float* out = (float*)d_out;

  float* ws    = (float*)d_ws;
  float* PT    = ws + OFF_PT;
  float* dyzT  = ws + OFF_DYZT;    // dyT, then reused as dzT
  float* cy    = ws + OFF_CY;
  float* cz    = ws + OFF_CZ;
  float* vol   = ws + OFF_VOL;
  float* volc  = ws + OFF_VOLC;
  float* aArr  = ws + OFF_A;
  float* fy    = ws + OFF_FY;
  float* fz    = ws + OFF_FZ;

  // zero atomic-accumulated region: cy + cz + vol + volc (contiguous)
  hipMemsetAsync(cy, 0, (size_t)(128000 + 160000 + 33) * sizeof(float), stream);

  k_init  <<<NPREP + 79, 256, 0, stream>>>(x, y, pz, tri, PT, volc);
  k_dy_vol<<<1250,       256, 0, stream>>>(PT, tri, dyzT, vol);
  k_gemm  <<<dim3(GKS, 32), 256, 0, stream>>>(dyzT, Vx, cy, N1n);
  k_factor<<<1, 1024, 0, stream>>>(cy, N1n, vol, volc, aArr, fy, 1);
  k_dz    <<<1250,       256, 0, stream>>>(PT, tri, cy, fy, dyzT);
  k_gemm  <<<dim3(GKS, 40), 256, 0, stream>>>(dyzT, Vxy, cz, NXn);
  k_factor<<<1, 1024, 0, stream>>>(cz, NXn, vol, volc, aArr, fz, 0);
  k_out   <<<1750,       256, 0, stream>>>(x, y, cy, cz, fy, fz, out);
}